// Round 2
// baseline (1169.751 us; speedup 1.0000x reference)
//
#include <hip/hip_runtime.h>
#include <stdint.h>

#define B_  128
#define G_  360
#define GI_ 174
#define EF_ 512
#define U_  512
#define AU_ 32
#define VOC_ 5000
#define T_  20

typedef short short8 __attribute__((ext_vector_type(8)));
typedef float floatx4 __attribute__((ext_vector_type(4)));

#define GLD16(gp, lp) __builtin_amdgcn_global_load_lds( \
    (const __attribute__((address_space(1))) void*)(gp), \
    (__attribute__((address_space(3))) void*)(lp), 16, 0, 0)

__device__ __forceinline__ unsigned short f2bf(float f){
  unsigned u = __float_as_uint(f);
  u += 0x7fffu + ((u>>16)&1u);
  return (unsigned short)(u>>16);
}
__device__ __forceinline__ float2 bfpair(unsigned u){
  float2 r; r.x = __uint_as_float(u<<16); r.y = __uint_as_float(u & 0xffff0000u); return r;
}
__device__ __forceinline__ unsigned packbf(float a, float b){
  return ((unsigned)f2bf(b)<<16) | (unsigned)f2bf(a);
}
__device__ __forceinline__ float sigmf(float x){ return 1.0f/(1.0f + __expf(-x)); }
__device__ __forceinline__ float tanhf_(float x){ return 1.0f - 2.0f/(1.0f + __expf(2.0f*x)); }
__device__ __forceinline__ float leaky_(float x){ return x >= 0.f ? x : 0.2f*x; }

// physical column for logical region-col cc (0..1023), row-parity e = row&7.
// XOR swizzle per 64-col block, 8-ushort (16B) units — matches GLD16-linear
// LDS staging + XOR-decoded ds_read_b128 (bank-conflict-free).
__device__ __forceinline__ int swzcol(int cc, int e){
  return (cc & ~63) | ((((cc>>3)&7) ^ e)<<3) | (cc&7);
}

// ====================== k_cvt: weight conversion / gather / transpose ==========
__global__ __launch_bounds__(256) void k_cvt(
    const int* __restrict__ text, const float* __restrict__ emb,
    const float* __restrict__ Wih, const float* __restrict__ Whh,
    const float* __restrict__ bih, const float* __restrict__ bhh,
    const float* __restrict__ W1, const float* __restrict__ b1,
    const float* __restrict__ encg, const float* __restrict__ encb,
    const float* __restrict__ dW1, const float* __restrict__ dW2,
    float* __restrict__ stats, unsigned short* __restrict__ Wstep,
    float* __restrict__ bias_sum, unsigned short* __restrict__ ASbuf,
    unsigned short* __restrict__ W1g, float* __restrict__ f1c,
    unsigned short* __restrict__ dW1t, unsigned short* __restrict__ dW2t)
{
  __shared__ float tile[64][65];
  const int blk = blockIdx.x, tid = threadIdx.x;
  if (blk < 90){
    int i = blk*1024 + tid*4;
    *(float4*)&stats[i] = make_float4(0.f,0.f,0.f,0.f);
  } else if (blk < 2138){
    int j = blk - 90;
    #pragma unroll
    for (int q=0;q<6;++q){
      int c = q*256 + tid;
      float v;
      if (c < 512)       v = Wih[(size_t)j*1024 + 512 + c];
      else if (c < 1024) v = Wih[(size_t)j*1024 + (c - 512)];
      else               v = Whh[(size_t)j*512 + (c - 1024)];
      // cols >= 512 (ctx|a region) stored pre-swizzled for k_gates
      int cd = c;
      if (c >= 512) cd = 512 + swzcol(c - 512, j&7);
      Wstep[(size_t)j*1536 + cd] = f2bf(v);
    }
  } else if (blk < 2146){
    int i = (blk-2138)*256 + tid;
    bias_sum[i] = bih[i] + bhh[i];
  } else if (blk < 4706){
    int r = blk - 2146; int t = r >> 7, b = r & 127;
    int idx = text[b*T_ + t];
    float2 v = *(const float2*)&emb[(size_t)idx*512 + 2*tid];
    ((unsigned*)ASbuf)[(((size_t)r*1536)>>1) + tid] = packbf(v.x, v.y);
  } else if (blk == 4706){
    if (tid < 32){
      float gw = 0.f, bw = 0.f;
      for (int k=0;k<512;++k){
        float wv = W1[(size_t)k*32 + tid];
        float gk = encg[k], bk = encb[k];
        W1g[(size_t)tid*512 + k] = f2bf(gk*wv);
        gw += gk*wv; bw += bk*wv;
      }
      f1c[tid] = gw; f1c[32+tid] = bw + b1[tid];
    }
  } else if (blk < 4739){
    int q = blk - 4707; int kt = q >> 2, nt = q & 3;
    int k0 = kt*64, n0 = nt*64;
    #pragma unroll
    for (int it=0; it<16; ++it){
      int idx = it*256 + tid; int kk = idx>>6, nn = idx&63;
      tile[kk][nn] = dW1[(size_t)(k0+kk)*256 + n0+nn];
    }
    __syncthreads();
    #pragma unroll
    for (int it=0; it<16; ++it){
      int idx = it*256 + tid; int nn = idx>>6, kk = idx&63;
      dW1t[(size_t)(n0+nn)*512 + k0+kk] = f2bf(tile[kk][nn]);
    }
  } else {
    int q = blk - 4739; int kt = q/80, nt = q - kt*80;
    int k0 = kt*64, n0 = nt*64;
    #pragma unroll
    for (int it=0; it<16; ++it){
      int idx = it*256 + tid; int kk = idx>>6, nn = idx&63;
      tile[kk][nn] = (n0+nn < VOC_) ? dW2[(size_t)(k0+kk)*VOC_ + n0+nn] : 0.f;
    }
    __syncthreads();
    #pragma unroll
    for (int it=0; it<16; ++it){
      int idx = it*256 + tid; int nn = idx>>6, kk = idx&63;
      dW2t[(size_t)(n0+nn)*256 + k0+kk] = f2bf(tile[kk][nn]);
    }
  }
}

// ====================== k_enc: per-group MFMA GEMM, pre-LN y + stats ==========
__device__ __forceinline__ int swz64(int row, int k){
  return row*64 + ((((k>>3) ^ (row&7)))<<3) + (k&7);
}
__global__ __launch_bounds__(256, 3) void k_enc(
    const float* __restrict__ features, const float* __restrict__ encW,
    const float* __restrict__ encB,
    unsigned short* __restrict__ ybuf, float* __restrict__ stats)
{
  __shared__ __align__(16) unsigned short As[128*64];
  __shared__ __align__(16) unsigned short Bs[128*64];
  const int g = blockIdx.y, n0 = blockIdx.x*128;
  const int tid = threadIdx.x, w = tid>>6, l = tid&63;
  const int quad = l>>4, col16 = l&15;
  const int m0w = (w>>1)*64, n0w = (w&1)*64;

  floatx4 acc[4][4];
  #pragma unroll
  for (int mi=0;mi<4;++mi)
    #pragma unroll
    for (int ni=0;ni<4;++ni)
      acc[mi][ni] = (floatx4){0.f,0.f,0.f,0.f};

  for (int c=0; c<3; ++c){
    if (c > 0) __syncthreads();
    // ---- A stage: 128 rows x 64 local-k, float4 global, b64 LDS writes
    #pragma unroll
    for (int q=0; q<8; ++q){
      int idx = q*256 + tid;            // 0..2047
      int row = idx >> 4;               // 0..127
      int kq  = idx & 15;               // which float4
      int kl  = kq*4;                   // local k
      int kgl = c*64 + kl;              // global k
      const float* fp = features + (size_t)row*(G_*GI_) + (size_t)g*GI_ + kgl;
      float4 v;
      if (kgl + 3 < GI_){
        v = *(const float4*)fp;
      } else {
        v.x = (kgl+0 < GI_) ? fp[0] : 0.f;
        v.y = (kgl+1 < GI_) ? fp[1] : 0.f;
        v.z = (kgl+2 < GI_) ? fp[2] : 0.f;
        v.w = (kgl+3 < GI_) ? fp[3] : 0.f;
      }
      int e = row*64 + (((kl>>3) ^ (row&7))<<3) + (kl&7);
      uint2 pk; pk.x = packbf(v.x, v.y); pk.y = packbf(v.z, v.w);
      *(uint2*)&As[e] = pk;
    }
    // ---- B stage: 64 local-k x 128 n (transposed), two batches of 8
    #pragma unroll
    for (int zb=0; zb<2; ++zb){
      #pragma unroll
      for (int z=0; z<8; ++z){
        int zz = zb*8 + z;
        int kk = w + 4*zz;              // local k 0..63
        int k  = c*64 + kk;
        if (k < GI_){
          const float* wp = encW + ((size_t)g*GI_ + k)*512 + n0;
          float2 v = *(const float2*)&wp[2*l];
          Bs[swz64(2*l,   kk)] = f2bf(v.x);
          Bs[swz64(2*l+1, kk)] = f2bf(v.y);
        } else {
          Bs[swz64(2*l,   kk)] = 0;
          Bs[swz64(2*l+1, kk)] = 0;
        }
      }
    }
    __syncthreads();
    #pragma unroll
    for (int it=0; it<2; ++it){
      int kk = it*32 + quad*8;
      short8 af[4], bfr[4];
      #pragma unroll
      for (int mi=0;mi<4;++mi){
        int row = m0w + mi*16 + col16;
        af[mi] = *(const short8*)&As[row*64 + (((kk>>3) ^ (row&7))<<3)];
      }
      #pragma unroll
      for (int ni=0;ni<4;++ni){
        int rowb = n0w + ni*16 + col16;
        bfr[ni] = *(const short8*)&Bs[rowb*64 + (((kk>>3) ^ (rowb&7))<<3)];
      }
      #pragma unroll
      for (int mi=0;mi<4;++mi)
        #pragma unroll
        for (int ni=0;ni<4;++ni)
          acc[mi][ni] = __builtin_amdgcn_mfma_f32_16x16x32_bf16(af[mi], bfr[ni], acc[mi][ni], 0,0,0);
    }
  }

  #pragma unroll
  for (int mi=0;mi<4;++mi){
    float sy[4] = {0.f,0.f,0.f,0.f};
    float sq[4] = {0.f,0.f,0.f,0.f};
    #pragma unroll
    for (int ni=0;ni<4;++ni){
      int nG = n0 + n0w + ni*16 + col16;
      float bv = encB[(size_t)g*512 + nG];
      #pragma unroll
      for (int reg=0;reg<4;++reg){
        int row = m0w + mi*16 + quad*4 + reg;
        float y = leaky_(acc[mi][ni][reg] + bv);
        unsigned short yh = f2bf(y);
        ybuf[((size_t)row*G_ + g)*512 + nG] = yh;
        float yr = __uint_as_float(((unsigned)yh)<<16);
        sy[reg] += yr; sq[reg] += yr*yr;
      }
    }
    #pragma unroll
    for (int reg=0; reg<4; ++reg){
      float a = sy[reg], bq = sq[reg];
      #pragma unroll
      for (int mk=1; mk<16; mk<<=1){ a += __shfl_xor(a, mk, 64); bq += __shfl_xor(bq, mk, 64); }
      if (col16 == 0){
        int row = m0w + mi*16 + quad*4 + reg;
        atomicAdd(&stats[((size_t)row*G_ + g)*2],     a);
        atomicAdd(&stats[((size_t)row*G_ + g)*2 + 1], bq);
      }
    }
  }
}

// ====================== generic bf16 MFMA GEMM (A[M][K], Bt[N][K]) ==========
template<int TN, int NBK, int MODE, int KSPLIT=1>
__global__ __launch_bounds__(256) void k_gemm(
    const unsigned short* __restrict__ A, int lda,
    const unsigned short* __restrict__ Bt, int ldb,
    const float* __restrict__ bias,
    float* __restrict__ outf, unsigned short* __restrict__ outh,
    const float* __restrict__ stats, float* __restrict__ stats2,
    const float* __restrict__ f1c)
{
  constexpr int NI = TN/32;
  __shared__ __align__(16) unsigned short As[128*64];
  __shared__ __align__(16) unsigned short Bs[TN*64];
  const int tid = threadIdx.x;
  const int w = tid >> 6, l = tid & 63;
  const int n0 = blockIdx.x * TN;
  const int ks = (KSPLIT > 1) ? blockIdx.y : 0;
  const int r0 = (KSPLIT > 1) ? 0 : blockIdx.y * 128;
  const int quad = l>>4, col16 = l&15;
  const int m0w = (w>>1)*64, n0w = (w&1)*(TN/2);
  const int arow = w*32, brow = w*(TN/4);

  const unsigned short* Ag = A + (size_t)(r0 + arow + (l>>3))*lda + (l&7)*8;
  const unsigned short* Bg = Bt + (size_t)(n0 + brow + (l>>3))*ldb + (l&7)*8;

  floatx4 acc[4][NI];
  #pragma unroll
  for (int mi=0;mi<4;++mi)
    #pragma unroll
    for (int ni=0;ni<NI;++ni)
      acc[mi][ni] = (floatx4){0.f,0.f,0.f,0.f};

  for (int it=0; it<NBK; ++it){
    int k0 = (ks*NBK + it)*64;
    #pragma unroll
    for (int q=0;q<4;++q)
      GLD16(Ag + (size_t)q*8*lda + k0, As + (arow + q*8)*64);
    #pragma unroll
    for (int q=0;q<TN/32;++q)
      GLD16(Bg + (size_t)q*8*ldb + k0, Bs + (brow + q*8)*64);
    __syncthreads();
    #pragma unroll
    for (int kc=0;kc<2;++kc){
      int koff = kc*32 + quad*8;
      short8 af[4], bfr[NI];
      #pragma unroll
      for (int mi=0;mi<4;++mi)
        af[mi] = *(const short8*)&As[(m0w + mi*16 + col16)*64 + koff];
      #pragma unroll
      for (int ni=0;ni<NI;++ni)
        bfr[ni] = *(const short8*)&Bs[(n0w + ni*16 + col16)*64 + koff];
      #pragma unroll
      for (int mi=0;mi<4;++mi)
        #pragma unroll
        for (int ni=0;ni<NI;++ni)
          acc[mi][ni] = __builtin_amdgcn_mfma_f32_16x16x32_bf16(af[mi], bfr[ni], acc[mi][ni], 0,0,0);
    }
    __syncthreads();
  }

  if constexpr (MODE == 0){
    float* op = outf + (size_t)ks*(128*2048);
    #pragma unroll
    for (int ni=0; ni<NI; ++ni){
      int nG = n0 + n0w + ni*16 + col16;
      float bv = (KSPLIT == 1 || ks == 0) ? bias[nG] : 0.f;
      #pragma unroll
      for (int mi=0; mi<4; ++mi)
        #pragma unroll
        for (int reg=0; reg<4; ++reg){
          int r = r0 + m0w + mi*16 + quad*4 + reg;
          op[(size_t)r*2048 + nG] = acc[mi][ni][reg] + bv;
        }
    }
  } else if constexpr (MODE == 1){
    int nG = n0w + col16;
    float gw = f1c[nG], bwv = f1c[32+nG];
    #pragma unroll
    for (int mi=0; mi<4; ++mi)
      #pragma unroll
      for (int reg=0; reg<4; ++reg){
        int r = r0 + m0w + mi*16 + quad*4 + reg;
        float2 st = *(const float2*)&stats[(size_t)r*2];
        float m = st.x * (1.f/512.f);
        float var = st.y * (1.f/512.f) - m*m;
        float rs = rsqrtf(var + 1e-5f);
        float v = rs*(acc[mi][0][reg] - m*gw) + bwv;
        v = v > 0.f ? v : 0.f;
        outf[(size_t)r*32 + nG] = v;
        if (((w&1)==0) && col16==0){
          stats2[(size_t)r*2] = m; stats2[(size_t)r*2+1] = rs;
        }
      }
  } else if constexpr (MODE == 2){
    #pragma unroll
    for (int ni=0; ni<NI; ++ni){
      int nG = n0 + n0w + ni*16 + col16;
      float bv = bias[nG];
      #pragma unroll
      for (int mi=0; mi<4; ++mi)
        #pragma unroll
        for (int reg=0; reg<4; ++reg){
          int r = r0 + m0w + mi*16 + quad*4 + reg;
          outh[(size_t)r*256 + nG] = f2bf(leaky_(acc[mi][ni][reg] + bv));
        }
    }
  } else {
    #pragma unroll
    for (int ni=0; ni<NI; ++ni){
      int nG = n0 + n0w + ni*16 + col16;
      if (nG < VOC_){
        float bv = bias[nG];
        #pragma unroll
        for (int mi=0; mi<4; ++mi)
          #pragma unroll
          for (int reg=0; reg<4; ++reg){
            int r = r0 + m0w + mi*16 + quad*4 + reg;
            int bb = r & 127, tt = r >> 7;
            outf[((size_t)bb*T_ + tt)*VOC_ + nG] = acc[mi][ni][reg] + bv;
          }
      }
    }
  }
}

// ====================== k_gates: per-step [128x2048x1024] split-K GEMM ==========
// Single-shot: whole K=128 slice resident in LDS, ONE barrier (no chunk chain).
// Reads pre-swizzled ASbuf/Wstep cols 512..1535; XOR-decoded ds_read_b128.
__global__ __launch_bounds__(256) void k_gates(
    const unsigned short* __restrict__ A,    // ASbuf + t*128*1536 + 512
    const unsigned short* __restrict__ Bt,   // Wstep
    float* __restrict__ outp)                // gsplit partials
{
  __shared__ __align__(16) unsigned short As[128*128];
  __shared__ __align__(16) unsigned short Bs[64*128];
  const int tid = threadIdx.x, w = tid>>6, l = tid&63;
  const int ks = blockIdx.y;      // 0..7  (K slice, 128 wide)
  const int n0 = blockIdx.x*64;
  const int quad = l>>4, col16 = l&15;
  const int m0w = (w>>1)*64, n0w = (w&1)*32;
  const int arow = w*32, brow = w*16;

  const unsigned short* Ag = A + (size_t)(arow + (l>>4))*1536 + ks*128 + (l&15)*8;
  const unsigned short* Bg = Bt + (size_t)(n0 + brow + (l>>4))*1536 + 512 + ks*128 + (l&15)*8;
  #pragma unroll
  for (int q=0;q<8;++q)
    GLD16(Ag + (size_t)q*4*1536, As + (arow + q*4)*128);
  #pragma unroll
  for (int q=0;q<4;++q)
    GLD16(Bg + (size_t)q*4*1536, Bs + (brow + q*4)*128);

  floatx4 acc[4][2];
  #pragma unroll
  for (int mi=0;mi<4;++mi)
    #pragma unroll
    for (int ni=0;ni<2;++ni)
      acc[mi][ni] = (floatx4){0.f,0.f,0.f,0.f};

  __syncthreads();
  #pragma unroll
  for (int kc=0;kc<4;++kc){
    int koff = kc*32 + quad*8;
    int kbase = koff & 64;
    int kx = (koff>>3)&7;
    short8 af[4], bfr[2];
    #pragma unroll
    for (int mi=0;mi<4;++mi){
      int row = m0w + mi*16 + col16;
      af[mi] = *(const short8*)&As[row*128 + kbase + ((kx ^ (row&7))<<3)];
    }
    #pragma unroll
    for (int ni=0;ni<2;++ni){
      int rowb = n0w + ni*16 + col16;
      bfr[ni] = *(const short8*)&Bs[rowb*128 + kbase + ((kx ^ (rowb&7))<<3)];
    }
    #pragma unroll
    for (int mi=0;mi<4;++mi)
      #pragma unroll
      for (int ni=0;ni<2;++ni)
        acc[mi][ni] = __builtin_amdgcn_mfma_f32_16x16x32_bf16(af[mi], bfr[ni], acc[mi][ni], 0,0,0);
  }

  float* op = outp + (size_t)ks*(128*2048);
  #pragma unroll
  for (int ni=0; ni<2; ++ni){
    int nG = n0 + n0w + ni*16 + col16;
    #pragma unroll
    for (int mi=0; mi<4; ++mi)
      #pragma unroll
      for (int reg=0; reg<4; ++reg){
        int r = m0w + mi*16 + quad*4 + reg;
        op[(size_t)r*2048 + nG] = acc[mi][ni][reg];
      }
  }
}

// ====================== fused LSTM cell + LN + next-step attention ==========
__global__ __launch_bounds__(256) void k_cellattn(
    const float* __restrict__ gall, const float* __restrict__ gtx,
    const float* __restrict__ c_in,
    float* __restrict__ c_out, const float* __restrict__ a0,
    const float* __restrict__ lng, const float* __restrict__ lnb,
    const float* __restrict__ W2, const float* __restrict__ b2,
    const float* __restrict__ Vv, const float* __restrict__ bV,
    const float* __restrict__ f1, const unsigned short* __restrict__ ybuf,
    const float* __restrict__ stats2,
    const float* __restrict__ encg, const float* __restrict__ encb,
    unsigned short* __restrict__ ASlot, unsigned short* __restrict__ a_bf,
    float* __restrict__ att_out, int t_att, int mode_cell, int do_attn)
{
  __shared__ float a_s[512];
  __shared__ float sc[G_];
  __shared__ float hred[8*32];
  __shared__ float h2s[32];
  __shared__ float red[16];
  __shared__ float mrs[2];
  const int b = blockIdx.x, tid = threadIdx.x;
  const int wv = tid >> 6, ln = tid & 63;

  if (mode_cell){
    float hl2[2];
    #pragma unroll
    for (int q=0;q<2;++q){
      int u = tid + q*256;
      size_t base = (size_t)b*2048;
      float gi = gtx[base+u];
      float gf = gtx[base+512+u];
      float gc = gtx[base+1024+u];
      float go = gtx[base+1536+u];
      #pragma unroll
      for (int s=0;s<8;++s){
        const float* gp = gall + (size_t)s*(128*2048) + base;
        gi += gp[u]; gf += gp[512+u]; gc += gp[1024+u]; go += gp[1536+u];
      }
      float c = sigmf(gf)*c_in[(size_t)b*512+u] + sigmf(gi)*tanhf_(gc);
      c_out[(size_t)b*512+u] = c;
      hl2[q] = leaky_(sigmf(go)*tanhf_(c));
    }
    float s = hl2[0]+hl2[1], ss = hl2[0]*hl2[0]+hl2[1]*hl2[1];
    #pragma unroll
    for (int mk=1;mk<64;mk<<=1){ s += __shfl_xor(s,mk,64); ss += __shfl_xor(ss,mk,64); }
    if (ln==0){ red[wv]=s; red[8+wv]=ss; }
    __syncthreads();
    if (tid==0){
      float S  = red[0]+red[1]+red[2]+red[3];
      float SS = red[8]+red[9]+red[10]+red[11];
      float mean = S*(1.f/512.f);
      float var  = SS*(1.f/512.f) - mean*mean;
      mrs[0]=mean; mrs[1]=rsqrtf(var+1e-5f);
    }
    __syncthreads();
    float mean = mrs[0], rstd = mrs[1];
    #pragma unroll
    for (int q=0;q<2;++q){
      int u = tid + q*256;
      float av = (hl2[q]-mean)*rstd*lng[u] + lnb[u];
      a_s[u] = av;
      a_bf[(size_t)b*512 + u] = f2bf(av);
      if (do_attn){
        int pc = swzcol(512 + u, b&7);
        ASlot[(size_t)b*1536 + 512 + pc] = f2bf(av);
      }
    }
  } else {
    #pragma unroll
    for (int q=0;q<2;++q){
      int u = tid + q*256;
      float av = a0[(size_t)b*512 + u];
      a_s[u] = av;
      int pc = swzcol(512 + u, b&7);
      ASlot[(size_t)b*1536 + 512 + pc] = f2bf(av);
    }
  }
  __syncthreads();
  if (!do_attn) return;

  {
    int u = tid & 31, ch = tid >> 5;
    float p = 0.f;
    const float* w2p = W2 + (size_t)ch*64*32 + u;
    const float* ap = a_s + ch*64;
    #pragma unroll 8
    for (int e=0;e<64;++e) p += ap[e]*w2p[(size_t)e*32];
    hred[ch*32+u] = p;
  }
  __syncthreads();
  if (tid < 32){
    float p = hred[tid];
    #pragma unroll
    for (int ch=1; ch<8; ++ch) p += hred[ch*32+tid];
    p += b2[tid];
    h2s[tid] = p>0.f? p:0.f;
  }
  __syncthreads();
  float bVv = bV[0];
  for (int gg = tid; gg < G_; gg += 256){
    const float* fp = f1 + ((size_t)b*G_ + gg)*32;
    float s = bVv;
    #pragma unroll
    for (int u=0;u<32;++u) s += tanhf_(fp[u] + h2s[u]) * Vv[u];
    sc[gg] = s;
  }
  __syncthreads();
  float mx = -1e30f;
  for (int gg=tid; gg<G_; gg+=256) mx = fmaxf(mx, sc[gg]);
  #pragma unroll
  for (int mk=1;mk<64;mk<<=1) mx = fmaxf(mx, __shfl_xor(mx,mk,64));
  if (ln==0) red[wv]=mx;
  __syncthreads();
  if (tid==0) red[0] = fmaxf(fmaxf(red[0],red[1]),fmaxf(red[2],red[3]));
  __syncthreads();
  mx = red[0];
  float psum = 0.f;
  for (int gg=tid; gg<G_; gg+=256){
    float e = __expf(sc[gg]-mx);
    sc[gg] = e; psum += e;
  }
  #pragma unroll
  for (int mk=1;mk<64;mk<<=1) psum += __shfl_xor(psum,mk,64);
  if (ln==0) red[8+wv]=psum;
  __syncthreads();
  if (tid==0) red[8] = red[8]+red[9]+red[10]+red[11];
  __syncthreads();
  float inv = 1.f/red[8];
  float Mop = 0.f;
  float* wout = att_out + ((size_t)b*T_ + t_att)*G_;
  for (int gg=tid; gg<G_; gg+=256){
    float wg = sc[gg]*inv;
    wout[gg] = wg;
    float2 st = *(const float2*)&stats2[((size_t)b*G_+gg)*2];
    sc[gg] = wg*st.y;
    Mop += wg*st.x*st.y;
  }
  #pragma unroll
  for (int mk=1;mk<64;mk<<=1) Mop += __shfl_xor(Mop,mk,64);
  if (ln==0) red[4+wv] = Mop;
  __syncthreads();
  if (tid==0) mrs[0] = red[4]+red[5]+red[6]+red[7];
  __syncthreads();
  float Mo = mrs[0];
  {
    const unsigned* fp = (const unsigned*)ybuf + ((size_t)b*G_)*256 + tid;
    float c0v=0.f, c1v=0.f;
    for (int gg=0; gg<G_; ++gg){
      float2 p = bfpair(fp[(size_t)gg*256]);
      float wq = sc[gg];
      c0v += wq*p.x; c1v += wq*p.y;
    }
    int e0 = 2*tid;
    float ctx0 = encg[e0]  *(c0v - Mo) + encb[e0];
    float ctx1 = encg[e0+1]*(c1v - Mo) + encb[e0+1];
    int pc = swzcol(2*tid, b&7);   // ctx region col pair (even)
    ((unsigned*)ASlot)[((size_t)b*1536 + 512 + pc)>>1] = packbf(ctx0, ctx1);
  }
}

// ====================== in-place row softmax over VOC ==========
__global__ __launch_bounds__(256) void k_softmax(float* __restrict__ outp)
{
  __shared__ float red[8];
  const size_t row = (size_t)blockIdx.x * VOC_;
  const int tid = threadIdx.x;
  const int wv = tid >> 6, ln = tid & 63;
  float v[20];
  float mx = -1e30f;
  #pragma unroll
  for (int k=0;k<20;++k){
    int idx = tid + k*256;
    v[k] = (idx < VOC_) ? outp[row+idx] : -1e30f;
    mx = fmaxf(mx, v[k]);
  }
  #pragma unroll
  for (int mk=1;mk<64;mk<<=1) mx = fmaxf(mx,__shfl_xor(mx,mk,64));
  if (ln==0) red[wv] = mx;
  __syncthreads();
  if (tid==0) red[0]=fmaxf(fmaxf(red[0],red[1]),fmaxf(red[2],red[3]));
  __syncthreads();
  mx = red[0];
  float s=0.f;
  #pragma unroll
  for (int k=0;k<20;++k){ v[k] = __expf(v[k]-mx); s += v[k]; }
  #pragma unroll
  for (int mk=1;mk<64;mk<<=1) s += __shfl_xor(s,mk,64);
  if (ln==0) red[4+wv]=s;
  __syncthreads();
  if (tid==0) red[4]=red[4]+red[5]+red[6]+red[7];
  __syncthreads();
  float inv = 1.f/red[4];
  #pragma unroll
  for (int k=0;k<20;++k){
    int idx = tid + k*256;
    if (idx < VOC_) outp[row+idx] = v[k]*inv;
  }
}

extern "C" void kernel_launch(void* const* d_in, const int* in_sizes, int n_in,
                              void* d_out, int out_size, void* d_ws, size_t ws_size,
                              hipStream_t stream) {
  const float* features = (const float*)d_in[0];
  const int*   text     = (const int*)d_in[1];
  const float* a0    = (const float*)d_in[2];
  const float* c0    = (const float*)d_in[3];
  const float* encW  = (const float*)d_in[4];
  const float* encB  = (const float*)d_in[5];
  const float* encLNg= (const float*)d_in[6];
  const float* encLNb= (const float*)d_in[7];
  const float* attnW1= (const float*)d_in[8];
  const float* attnb1= (const float*)d_in[9];
  const float* attnW2= (const float*)d_in[10];
  const float* attnb2= (const float*)d_in[11];
  const float* attnV = (const float*)d_in[12];
  const float* attnbV= (const float*)d_in[13];
  const float* emb   = (const float*)d_in[14];
  const float* Wih   = (const float*)d_in[15];
  const float* Whh   = (const float*)d_in[16];
  const float* bih   = (const float*)d_in[17];
  const float* bhh   = (const float*)d_in[18];
  const float* lng   = (const float*)d_in[19];
  const float* lnb   = (const float*)d_in[20];
  const float* dW1   = (const float*)d_in[21];
  const float* db1   = (const float*)d_in[22];
  const float* dW2   = (const float*)d_in[23];
  const float* db2   = (const float*)d_in[24];

  uint8_t* w8 = (uint8_t*)d_ws;
  unsigned short* ybuf   = (unsigned short*)(w8);              // 47,185,920
  float*          stats  = (float*)(w8 + 47185920);            //    368,640
  float*          stats2 = (float*)(w8 + 47554560);            //    368,640
  float*          f1b    = (float*)(w8 + 47923200);            //  5,898,240
  unsigned short* ASbuf  = (unsigned short*)(w8 + 53821440);   //  7,864,320
  unsigned short* Wstep  = (unsigned short*)(w8 + 61685760);   //  6,291,456
  float*          bias_sum=(float*)(w8 + 67977216);            //      8,192
  unsigned short* W1g    = (unsigned short*)(w8 + 67985408);   //     32,768
  float*          f1c    = (float*)(w8 + 68018176);            //        256
  unsigned short* dW1t   = (unsigned short*)(w8 + 68018432);   //    262,144
  unsigned short* dW2t   = (unsigned short*)(w8 + 68280576);   //  2,621,440
  float*          cws    = (float*)(w8 + 71950592);            //    262,144
  unsigned short* a_bf   = (unsigned short*)(w8 + 72212736);   //  2,621,440
  unsigned short* d1bf   = (unsigned short*)(w8 + 74834176);   //  1,310,720

  float* outp = (float*)d_out;
  float* att  = outp + 12800000;   // [B][T][G]
  // scratch inside the (dead until decoder) output buffer:
  //   gsplit: 8 x [128][2048] f32 split-K partials   (8 MB)
  //   gtxt:  [2560][2048] f32 text-part + bias       (21 MB)
  float* gsplit = outp;
  float* gtxt   = outp + 8*128*2048;

  hipLaunchKernelGGL(k_cvt, dim3(5059), dim3(256), 0, stream,
                     text, emb, Wih, Whh, bih, bhh, attnW1, attnb1,
                     encLNg, encLNb, dW1, dW2,
                     stats, Wstep, bias_sum, ASbuf, W1g, f1c, dW1t, dW2t);
  hipLaunchKernelGGL(k_enc, dim3(4,360), dim3(256), 0, stream,
                     features, encW, encB, ybuf, stats);
  // precompute text-part of the gates for ALL steps: gtxt = txt @ W_txt^T + bias
  hipLaunchKernelGGL((k_gemm<64,8,0>), dim3(32,20), dim3(256), 0, stream,
                     ASbuf, 1536, Wstep, 1536, bias_sum,
                     gtxt, (unsigned short*)nullptr,
                     (const float*)nullptr, (float*)nullptr, (const float*)nullptr);
  hipLaunchKernelGGL((k_gemm<32,8,1>), dim3(1,360), dim3(256), 0, stream,
                     ybuf, 512, W1g, 512, (const float*)nullptr,
                     f1b, (unsigned short*)nullptr, stats, stats2, f1c);
  hipLaunchKernelGGL(k_cellattn, dim3(128), dim3(256), 0, stream,
                     gsplit, gtxt, c0, cws, a0, lng, lnb, attnW2, attnb2, attnV, attnbV,
                     f1b, ybuf, stats2, encLNg, encLNb,
                     ASbuf, a_bf, att, 0, 0, 1);
  for (int t=0; t<T_; ++t){
    hipLaunchKernelGGL(k_gates, dim3(32,8), dim3(256), 0, stream,
                       ASbuf + (size_t)t*128*1536 + 512, Wstep, gsplit);
    int da = (t < T_-1) ? 1 : 0;
    unsigned short* slot = ASbuf + (size_t)((t+1 < T_) ? (t+1) : 0)*128*1536;
    hipLaunchKernelGGL(k_cellattn, dim3(128), dim3(256), 0, stream,
                       gsplit, gtxt + (size_t)t*128*2048, (t==0)?c0:cws, cws, a0, lng, lnb,
                       attnW2, attnb2, attnV, attnbV,
                       f1b, ybuf, stats2, encLNg, encLNb,
                       slot, a_bf + (size_t)t*128*512, att, t+1, 1, da);
  }
  hipLaunchKernelGGL((k_gemm<128,8,2>), dim3(2,20), dim3(256), 0, stream,
                     a_bf, 512, dW1t, 512, db1,
                     (float*)nullptr, d1bf, (const float*)nullptr, (float*)nullptr,
                     (const float*)nullptr);
  hipLaunchKernelGGL((k_gemm<128,4,3>), dim3(40,20), dim3(256), 0, stream,
                     d1bf, 256, dW2t, 256, db2,
                     outp, (unsigned short*)nullptr, (const float*)nullptr,
                     (float*)nullptr, (const float*)nullptr);
  hipLaunchKernelGGL(k_softmax, dim3(2560), dim3(256), 0, stream, outp);
}

// Round 3
// 1011.275 us; speedup vs baseline: 1.1567x; 1.1567x over previous
//
#include <hip/hip_runtime.h>
#include <stdint.h>

#define B_  128
#define G_  360
#define GI_ 174
#define EF_ 512
#define U_  512
#define AU_ 32
#define VOC_ 5000
#define T_  20

typedef short short8 __attribute__((ext_vector_type(8)));
typedef float floatx4 __attribute__((ext_vector_type(4)));

#define GLD16(gp, lp) __builtin_amdgcn_global_load_lds( \
    (const __attribute__((address_space(1))) void*)(gp), \
    (__attribute__((address_space(3))) void*)(lp), 16, 0, 0)

__device__ __forceinline__ unsigned short f2bf(float f){
  unsigned u = __float_as_uint(f);
  u += 0x7fffu + ((u>>16)&1u);
  return (unsigned short)(u>>16);
}
__device__ __forceinline__ float2 bfpair(unsigned u){
  float2 r; r.x = __uint_as_float(u<<16); r.y = __uint_as_float(u & 0xffff0000u); return r;
}
__device__ __forceinline__ unsigned packbf(float a, float b){
  return ((unsigned)f2bf(b)<<16) | (unsigned)f2bf(a);
}
__device__ __forceinline__ float sigmf(float x){ return 1.0f/(1.0f + __expf(-x)); }
__device__ __forceinline__ float tanhf_(float x){ return 1.0f - 2.0f/(1.0f + __expf(2.0f*x)); }
__device__ __forceinline__ float leaky_(float x){ return x >= 0.f ? x : 0.2f*x; }

// physical column for logical region-col cc (0..1023), row-parity e = row&7.
__device__ __forceinline__ int swzcol(int cc, int e){
  return (cc & ~63) | ((((cc>>3)&7) ^ e)<<3) | (cc&7);
}

// ====================== k_cvt: weight conversion / gather / transpose ==========
__global__ __launch_bounds__(256) void k_cvt(
    const int* __restrict__ text, const float* __restrict__ emb,
    const float* __restrict__ Wih, const float* __restrict__ Whh,
    const float* __restrict__ bih, const float* __restrict__ bhh,
    const float* __restrict__ W1, const float* __restrict__ b1,
    const float* __restrict__ encg, const float* __restrict__ encb,
    const float* __restrict__ dW1, const float* __restrict__ dW2,
    float* __restrict__ stats, unsigned short* __restrict__ Wstep,
    float* __restrict__ bias_sum, unsigned short* __restrict__ ASbuf,
    unsigned short* __restrict__ W1g, float* __restrict__ f1c,
    unsigned short* __restrict__ dW1t, unsigned short* __restrict__ dW2t)
{
  __shared__ float tile[64][65];
  const int blk = blockIdx.x, tid = threadIdx.x;
  if (blk < 90){
    int i = blk*1024 + tid*4;
    *(float4*)&stats[i] = make_float4(0.f,0.f,0.f,0.f);
  } else if (blk < 2138){
    int j = blk - 90;
    #pragma unroll
    for (int q=0;q<6;++q){
      int c = q*256 + tid;
      float v;
      if (c < 512)       v = Wih[(size_t)j*1024 + 512 + c];
      else if (c < 1024) v = Wih[(size_t)j*1024 + (c - 512)];
      else               v = Whh[(size_t)j*512 + (c - 1024)];
      int cd = c;
      if (c >= 512) cd = 512 + swzcol(c - 512, j&7);
      Wstep[(size_t)j*1536 + cd] = f2bf(v);
    }
  } else if (blk < 2146){
    int i = (blk-2138)*256 + tid;
    bias_sum[i] = bih[i] + bhh[i];
  } else if (blk < 4706){
    int r = blk - 2146; int t = r >> 7, b = r & 127;
    int idx = text[b*T_ + t];
    float2 v = *(const float2*)&emb[(size_t)idx*512 + 2*tid];
    ((unsigned*)ASbuf)[(((size_t)r*1536)>>1) + tid] = packbf(v.x, v.y);
  } else if (blk == 4706){
    if (tid < 32){
      float gw = 0.f, bw = 0.f;
      for (int k=0;k<512;++k){
        float wv = W1[(size_t)k*32 + tid];
        float gk = encg[k], bk = encb[k];
        W1g[(size_t)tid*512 + k] = f2bf(gk*wv);
        gw += gk*wv; bw += bk*wv;
      }
      f1c[tid] = gw; f1c[32+tid] = bw + b1[tid];
    }
  } else if (blk < 4739){
    int q = blk - 4707; int kt = q >> 2, nt = q & 3;
    int k0 = kt*64, n0 = nt*64;
    #pragma unroll
    for (int it=0; it<16; ++it){
      int idx = it*256 + tid; int kk = idx>>6, nn = idx&63;
      tile[kk][nn] = dW1[(size_t)(k0+kk)*256 + n0+nn];
    }
    __syncthreads();
    #pragma unroll
    for (int it=0; it<16; ++it){
      int idx = it*256 + tid; int nn = idx>>6, kk = idx&63;
      dW1t[(size_t)(n0+nn)*512 + k0+kk] = f2bf(tile[kk][nn]);
    }
  } else {
    int q = blk - 4739; int kt = q/80, nt = q - kt*80;
    int k0 = kt*64, n0 = nt*64;
    #pragma unroll
    for (int it=0; it<16; ++it){
      int idx = it*256 + tid; int kk = idx>>6, nn = idx&63;
      tile[kk][nn] = (n0+nn < VOC_) ? dW2[(size_t)(k0+kk)*VOC_ + n0+nn] : 0.f;
    }
    __syncthreads();
    #pragma unroll
    for (int it=0; it<16; ++it){
      int idx = it*256 + tid; int nn = idx>>6, kk = idx&63;
      dW2t[(size_t)(n0+nn)*256 + k0+kk] = f2bf(tile[kk][nn]);
    }
  }
}

// ====================== k_enc: per-group MFMA GEMM, pre-LN y + stats ==========
// 512 threads: 8 waves in a 4(M) x 2(N) grid, per-wave tile 32x64 -> acc is
// only 2x4 floatx4 (32 regs). Smaller per-thread state => no spills, and
// ~4 waves/SIMD occupancy instead of 2. LDS 32 KB (2 blocks/CU).
__device__ __forceinline__ int swz64(int row, int k){
  return row*64 + ((((k>>3) ^ (row&7)))<<3) + (k&7);
}
__global__ __launch_bounds__(512) void k_enc(
    const float* __restrict__ features, const float* __restrict__ encW,
    const float* __restrict__ encB,
    unsigned short* __restrict__ ybuf, float* __restrict__ stats)
{
  __shared__ __align__(16) unsigned short As[128*64];
  __shared__ __align__(16) unsigned short Bs[128*64];
  const int g = blockIdx.y, n0 = blockIdx.x*128;
  const int tid = threadIdx.x, w = tid>>6, l = tid&63;
  const int quad = l>>4, col16 = l&15;
  const int wm = w>>1, wn = w&1;
  const int m0w = wm*32, n0w = wn*64;

  floatx4 acc[2][4];
  #pragma unroll
  for (int mi=0;mi<2;++mi)
    #pragma unroll
    for (int ni=0;ni<4;++ni)
      acc[mi][ni] = (floatx4){0.f,0.f,0.f,0.f};

  for (int c=0; c<3; ++c){
    if (c > 0) __syncthreads();
    // ---- A stage: 128 rows x 64 local-k; 2048 float4 units / 512 thr = 4 ea
    #pragma unroll
    for (int q=0; q<4; ++q){
      int idx = q*512 + tid;            // 0..2047
      int row = idx >> 4;               // 0..127
      int kl  = (idx & 15)*4;           // local k
      int kgl = c*64 + kl;              // global k
      const float* fp = features + (size_t)row*(G_*GI_) + (size_t)g*GI_ + kgl;
      float4 v;
      if (kgl + 3 < GI_){
        v = *(const float4*)fp;
      } else {
        v.x = (kgl+0 < GI_) ? fp[0] : 0.f;
        v.y = (kgl+1 < GI_) ? fp[1] : 0.f;
        v.z = (kgl+2 < GI_) ? fp[2] : 0.f;
        v.w = (kgl+3 < GI_) ? fp[3] : 0.f;
      }
      int e = row*64 + (((kl>>3) ^ (row&7))<<3) + (kl&7);
      uint2 pk; pk.x = packbf(v.x, v.y); pk.y = packbf(v.z, v.w);
      *(uint2*)&As[e] = pk;
    }
    // ---- B stage: 64 local-k x 128 n (transposed); 8 float2 per thread
    #pragma unroll
    for (int z=0; z<8; ++z){
      int kk = (tid>>6) + 8*z;          // local k 0..63
      int k  = c*64 + kk;
      int nn = (tid&63)*2;
      if (k < GI_){
        const float* wp = encW + ((size_t)g*GI_ + k)*512 + n0 + nn;
        float2 v = *(const float2*)wp;
        Bs[swz64(nn,   kk)] = f2bf(v.x);
        Bs[swz64(nn+1, kk)] = f2bf(v.y);
      } else {
        Bs[swz64(nn,   kk)] = 0;
        Bs[swz64(nn+1, kk)] = 0;
      }
    }
    __syncthreads();
    #pragma unroll
    for (int it=0; it<2; ++it){
      int kk = it*32 + quad*8;
      short8 af[2], bfr[4];
      #pragma unroll
      for (int mi=0;mi<2;++mi){
        int row = m0w + mi*16 + col16;
        af[mi] = *(const short8*)&As[row*64 + (((kk>>3) ^ (row&7))<<3)];
      }
      #pragma unroll
      for (int ni=0;ni<4;++ni){
        int rowb = n0w + ni*16 + col16;
        bfr[ni] = *(const short8*)&Bs[rowb*64 + (((kk>>3) ^ (rowb&7))<<3)];
      }
      #pragma unroll
      for (int mi=0;mi<2;++mi)
        #pragma unroll
        for (int ni=0;ni<4;++ni)
          acc[mi][ni] = __builtin_amdgcn_mfma_f32_16x16x32_bf16(af[mi], bfr[ni], acc[mi][ni], 0,0,0);
    }
  }

  #pragma unroll
  for (int mi=0;mi<2;++mi){
    float sy[4] = {0.f,0.f,0.f,0.f};
    float sq[4] = {0.f,0.f,0.f,0.f};
    #pragma unroll
    for (int ni=0;ni<4;++ni){
      int nG = n0 + n0w + ni*16 + col16;
      float bv = encB[(size_t)g*512 + nG];
      #pragma unroll
      for (int reg=0;reg<4;++reg){
        int row = m0w + mi*16 + quad*4 + reg;
        float y = leaky_(acc[mi][ni][reg] + bv);
        unsigned short yh = f2bf(y);
        ybuf[((size_t)row*G_ + g)*512 + nG] = yh;
        float yr = __uint_as_float(((unsigned)yh)<<16);
        sy[reg] += yr; sq[reg] += yr*yr;
      }
    }
    #pragma unroll
    for (int reg=0; reg<4; ++reg){
      float a = sy[reg], bq = sq[reg];
      #pragma unroll
      for (int mk=1; mk<16; mk<<=1){ a += __shfl_xor(a, mk, 64); bq += __shfl_xor(bq, mk, 64); }
      if (col16 == 0){
        int row = m0w + mi*16 + quad*4 + reg;
        atomicAdd(&stats[((size_t)row*G_ + g)*2],     a);
        atomicAdd(&stats[((size_t)row*G_ + g)*2 + 1], bq);
      }
    }
  }
}

// ====================== generic bf16 MFMA GEMM (A[M][K], Bt[N][K]) ==========
template<int TN, int NBK, int MODE, int KSPLIT=1>
__global__ __launch_bounds__(256) void k_gemm(
    const unsigned short* __restrict__ A, int lda,
    const unsigned short* __restrict__ Bt, int ldb,
    const float* __restrict__ bias,
    float* __restrict__ outf, unsigned short* __restrict__ outh,
    const float* __restrict__ stats, float* __restrict__ stats2,
    const float* __restrict__ f1c)
{
  constexpr int NI = TN/32;
  __shared__ __align__(16) unsigned short As[128*64];
  __shared__ __align__(16) unsigned short Bs[TN*64];
  const int tid = threadIdx.x;
  const int w = tid >> 6, l = tid & 63;
  const int n0 = blockIdx.x * TN;
  const int ks = (KSPLIT > 1) ? blockIdx.y : 0;
  const int r0 = (KSPLIT > 1) ? 0 : blockIdx.y * 128;
  const int quad = l>>4, col16 = l&15;
  const int m0w = (w>>1)*64, n0w = (w&1)*(TN/2);
  const int arow = w*32, brow = w*(TN/4);

  const unsigned short* Ag = A + (size_t)(r0 + arow + (l>>3))*lda + (l&7)*8;
  const unsigned short* Bg = Bt + (size_t)(n0 + brow + (l>>3))*ldb + (l&7)*8;

  floatx4 acc[4][NI];
  #pragma unroll
  for (int mi=0;mi<4;++mi)
    #pragma unroll
    for (int ni=0;ni<NI;++ni)
      acc[mi][ni] = (floatx4){0.f,0.f,0.f,0.f};

  for (int it=0; it<NBK; ++it){
    int k0 = (ks*NBK + it)*64;
    #pragma unroll
    for (int q=0;q<4;++q)
      GLD16(Ag + (size_t)q*8*lda + k0, As + (arow + q*8)*64);
    #pragma unroll
    for (int q=0;q<TN/32;++q)
      GLD16(Bg + (size_t)q*8*ldb + k0, Bs + (brow + q*8)*64);
    __syncthreads();
    #pragma unroll
    for (int kc=0;kc<2;++kc){
      int koff = kc*32 + quad*8;
      short8 af[4], bfr[NI];
      #pragma unroll
      for (int mi=0;mi<4;++mi)
        af[mi] = *(const short8*)&As[(m0w + mi*16 + col16)*64 + koff];
      #pragma unroll
      for (int ni=0;ni<NI;++ni)
        bfr[ni] = *(const short8*)&Bs[(n0w + ni*16 + col16)*64 + koff];
      #pragma unroll
      for (int mi=0;mi<4;++mi)
        #pragma unroll
        for (int ni=0;ni<NI;++ni)
          acc[mi][ni] = __builtin_amdgcn_mfma_f32_16x16x32_bf16(af[mi], bfr[ni], acc[mi][ni], 0,0,0);
    }
    __syncthreads();
  }

  if constexpr (MODE == 0){
    float* op = outf + (size_t)ks*(128*2048);
    #pragma unroll
    for (int ni=0; ni<NI; ++ni){
      int nG = n0 + n0w + ni*16 + col16;
      float bv = (KSPLIT == 1 || ks == 0) ? bias[nG] : 0.f;
      #pragma unroll
      for (int mi=0; mi<4; ++mi)
        #pragma unroll
        for (int reg=0; reg<4; ++reg){
          int r = r0 + m0w + mi*16 + quad*4 + reg;
          op[(size_t)r*2048 + nG] = acc[mi][ni][reg] + bv;
        }
    }
  } else if constexpr (MODE == 1){
    int nG = n0w + col16;
    float gw = f1c[nG], bwv = f1c[32+nG];
    #pragma unroll
    for (int mi=0; mi<4; ++mi)
      #pragma unroll
      for (int reg=0; reg<4; ++reg){
        int r = r0 + m0w + mi*16 + quad*4 + reg;
        float2 st = *(const float2*)&stats[(size_t)r*2];
        float m = st.x * (1.f/512.f);
        float var = st.y * (1.f/512.f) - m*m;
        float rs = rsqrtf(var + 1e-5f);
        float v = rs*(acc[mi][0][reg] - m*gw) + bwv;
        v = v > 0.f ? v : 0.f;
        outf[(size_t)r*32 + nG] = v;
        if (((w&1)==0) && col16==0){
          stats2[(size_t)r*2] = m; stats2[(size_t)r*2+1] = rs;
        }
      }
  } else if constexpr (MODE == 2){
    #pragma unroll
    for (int ni=0; ni<NI; ++ni){
      int nG = n0 + n0w + ni*16 + col16;
      float bv = bias[nG];
      #pragma unroll
      for (int mi=0; mi<4; ++mi)
        #pragma unroll
        for (int reg=0; reg<4; ++reg){
          int r = r0 + m0w + mi*16 + quad*4 + reg;
          outh[(size_t)r*256 + nG] = f2bf(leaky_(acc[mi][ni][reg] + bv));
        }
    }
  } else {
    #pragma unroll
    for (int ni=0; ni<NI; ++ni){
      int nG = n0 + n0w + ni*16 + col16;
      if (nG < VOC_){
        float bv = bias[nG];
        #pragma unroll
        for (int mi=0; mi<4; ++mi)
          #pragma unroll
          for (int reg=0; reg<4; ++reg){
            int r = r0 + m0w + mi*16 + quad*4 + reg;
            int bb = r & 127, tt = r >> 7;
            outf[((size_t)bb*T_ + tt)*VOC_ + nG] = acc[mi][ni][reg] + bv;
          }
      }
    }
  }
}

// ====================== k_gates: per-step [128x2048x1024] split-K GEMM ==========
__global__ __launch_bounds__(256) void k_gates(
    const unsigned short* __restrict__ A,    // ASbuf + t*128*1536 + 512
    const unsigned short* __restrict__ Bt,   // Wstep
    float* __restrict__ outp)                // gsplit partials
{
  __shared__ __align__(16) unsigned short As[128*128];
  __shared__ __align__(16) unsigned short Bs[64*128];
  const int tid = threadIdx.x, w = tid>>6, l = tid&63;
  const int ks = blockIdx.y;      // 0..7  (K slice, 128 wide)
  const int n0 = blockIdx.x*64;
  const int quad = l>>4, col16 = l&15;
  const int m0w = (w>>1)*64, n0w = (w&1)*32;
  const int arow = w*32, brow = w*16;

  const unsigned short* Ag = A + (size_t)(arow + (l>>4))*1536 + ks*128 + (l&15)*8;
  const unsigned short* Bg = Bt + (size_t)(n0 + brow + (l>>4))*1536 + 512 + ks*128 + (l&15)*8;
  #pragma unroll
  for (int q=0;q<8;++q)
    GLD16(Ag + (size_t)q*4*1536, As + (arow + q*4)*128);
  #pragma unroll
  for (int q=0;q<4;++q)
    GLD16(Bg + (size_t)q*4*1536, Bs + (brow + q*4)*128);

  floatx4 acc[4][2];
  #pragma unroll
  for (int mi=0;mi<4;++mi)
    #pragma unroll
    for (int ni=0;ni<2;++ni)
      acc[mi][ni] = (floatx4){0.f,0.f,0.f,0.f};

  __syncthreads();
  #pragma unroll
  for (int kc=0;kc<4;++kc){
    int koff = kc*32 + quad*8;
    int kbase = koff & 64;
    int kx = (koff>>3)&7;
    short8 af[4], bfr[2];
    #pragma unroll
    for (int mi=0;mi<4;++mi){
      int row = m0w + mi*16 + col16;
      af[mi] = *(const short8*)&As[row*128 + kbase + ((kx ^ (row&7))<<3)];
    }
    #pragma unroll
    for (int ni=0;ni<2;++ni){
      int rowb = n0w + ni*16 + col16;
      bfr[ni] = *(const short8*)&Bs[rowb*128 + kbase + ((kx ^ (rowb&7))<<3)];
    }
    #pragma unroll
    for (int mi=0;mi<4;++mi)
      #pragma unroll
      for (int ni=0;ni<2;++ni)
        acc[mi][ni] = __builtin_amdgcn_mfma_f32_16x16x32_bf16(af[mi], bfr[ni], acc[mi][ni], 0,0,0);
  }

  float* op = outp + (size_t)ks*(128*2048);
  #pragma unroll
  for (int ni=0; ni<2; ++ni){
    int nG = n0 + n0w + ni*16 + col16;
    #pragma unroll
    for (int mi=0; mi<4; ++mi)
      #pragma unroll
      for (int reg=0; reg<4; ++reg){
        int r = m0w + mi*16 + quad*4 + reg;
        op[(size_t)r*2048 + nG] = acc[mi][ni][reg];
      }
  }
}

// ====================== fused LSTM cell + LN + next-step attention ==========
__global__ __launch_bounds__(256) void k_cellattn(
    const float* __restrict__ gall, const float* __restrict__ gtx,
    const float* __restrict__ c_in,
    float* __restrict__ c_out, const float* __restrict__ a0,
    const float* __restrict__ lng, const float* __restrict__ lnb,
    const float* __restrict__ W2, const float* __restrict__ b2,
    const float* __restrict__ Vv, const float* __restrict__ bV,
    const float* __restrict__ f1, const unsigned short* __restrict__ ybuf,
    const float* __restrict__ stats2,
    const float* __restrict__ encg, const float* __restrict__ encb,
    unsigned short* __restrict__ ASlot, unsigned short* __restrict__ a_bf,
    float* __restrict__ att_out, int t_att, int mode_cell, int do_attn)
{
  __shared__ float a_s[512];
  __shared__ float sc[G_];
  __shared__ float hred[8*32];
  __shared__ float h2s[32];
  __shared__ float red[16];
  __shared__ float mrs[2];
  __shared__ float2 cred[4][256];   // ctx partials per wave
  const int b = blockIdx.x, tid = threadIdx.x;
  const int wv = tid >> 6, ln = tid & 63;

  if (mode_cell){
    float hl2[2];
    #pragma unroll
    for (int q=0;q<2;++q){
      int u = tid + q*256;
      size_t base = (size_t)b*2048;
      float gi = gtx[base+u];
      float gf = gtx[base+512+u];
      float gc = gtx[base+1024+u];
      float go = gtx[base+1536+u];
      #pragma unroll
      for (int s=0;s<8;++s){
        const float* gp = gall + (size_t)s*(128*2048) + base;
        gi += gp[u]; gf += gp[512+u]; gc += gp[1024+u]; go += gp[1536+u];
      }
      float c = sigmf(gf)*c_in[(size_t)b*512+u] + sigmf(gi)*tanhf_(gc);
      c_out[(size_t)b*512+u] = c;
      hl2[q] = leaky_(sigmf(go)*tanhf_(c));
    }
    float s = hl2[0]+hl2[1], ss = hl2[0]*hl2[0]+hl2[1]*hl2[1];
    #pragma unroll
    for (int mk=1;mk<64;mk<<=1){ s += __shfl_xor(s,mk,64); ss += __shfl_xor(ss,mk,64); }
    if (ln==0){ red[wv]=s; red[8+wv]=ss; }
    __syncthreads();
    if (tid==0){
      float S  = red[0]+red[1]+red[2]+red[3];
      float SS = red[8]+red[9]+red[10]+red[11];
      float mean = S*(1.f/512.f);
      float var  = SS*(1.f/512.f) - mean*mean;
      mrs[0]=mean; mrs[1]=rsqrtf(var+1e-5f);
    }
    __syncthreads();
    float mean = mrs[0], rstd = mrs[1];
    #pragma unroll
    for (int q=0;q<2;++q){
      int u = tid + q*256;
      float av = (hl2[q]-mean)*rstd*lng[u] + lnb[u];
      a_s[u] = av;
      a_bf[(size_t)b*512 + u] = f2bf(av);
      if (do_attn){
        int pc = swzcol(512 + u, b&7);
        ASlot[(size_t)b*1536 + 512 + pc] = f2bf(av);
      }
    }
  } else {
    #pragma unroll
    for (int q=0;q<2;++q){
      int u = tid + q*256;
      float av = a0[(size_t)b*512 + u];
      a_s[u] = av;
      int pc = swzcol(512 + u, b&7);
      ASlot[(size_t)b*1536 + 512 + pc] = f2bf(av);
    }
  }
  __syncthreads();
  if (!do_attn) return;

  {
    int u = tid & 31, ch = tid >> 5;
    float p = 0.f;
    const float* w2p = W2 + (size_t)ch*64*32 + u;
    const float* ap = a_s + ch*64;
    #pragma unroll 8
    for (int e=0;e<64;++e) p += ap[e]*w2p[(size_t)e*32];
    hred[ch*32+u] = p;
  }
  __syncthreads();
  if (tid < 32){
    float p = hred[tid];
    #pragma unroll
    for (int ch=1; ch<8; ++ch) p += hred[ch*32+tid];
    p += b2[tid];
    h2s[tid] = p>0.f? p:0.f;
  }
  __syncthreads();
  float bVv = bV[0];
  for (int gg = tid; gg < G_; gg += 256){
    const float* fp = f1 + ((size_t)b*G_ + gg)*32;
    float s = bVv;
    #pragma unroll
    for (int u=0;u<32;++u) s += tanhf_(fp[u] + h2s[u]) * Vv[u];
    sc[gg] = s;
  }
  __syncthreads();
  float mx = -1e30f;
  for (int gg=tid; gg<G_; gg+=256) mx = fmaxf(mx, sc[gg]);
  #pragma unroll
  for (int mk=1;mk<64;mk<<=1) mx = fmaxf(mx, __shfl_xor(mx,mk,64));
  if (ln==0) red[wv]=mx;
  __syncthreads();
  if (tid==0) red[0] = fmaxf(fmaxf(red[0],red[1]),fmaxf(red[2],red[3]));
  __syncthreads();
  mx = red[0];
  float psum = 0.f;
  for (int gg=tid; gg<G_; gg+=256){
    float e = __expf(sc[gg]-mx);
    sc[gg] = e; psum += e;
  }
  #pragma unroll
  for (int mk=1;mk<64;mk<<=1) psum += __shfl_xor(psum,mk,64);
  if (ln==0) red[8+wv]=psum;
  __syncthreads();
  if (tid==0) red[8] = red[8]+red[9]+red[10]+red[11];
  __syncthreads();
  float inv = 1.f/red[8];
  float Mop = 0.f;
  float* wout = att_out + ((size_t)b*T_ + t_att)*G_;
  for (int gg=tid; gg<G_; gg+=256){
    float wg = sc[gg]*inv;
    wout[gg] = wg;
    float2 st = *(const float2*)&stats2[((size_t)b*G_+gg)*2];
    sc[gg] = wg*st.y;
    Mop += wg*st.x*st.y;
  }
  #pragma unroll
  for (int mk=1;mk<64;mk<<=1) Mop += __shfl_xor(Mop,mk,64);
  if (ln==0) red[4+wv] = Mop;
  __syncthreads();
  if (tid==0) mrs[0] = red[4]+red[5]+red[6]+red[7];
  __syncthreads();
  float Mo = mrs[0];
  // ---- ctx matvec: g-loop split across the 4 waves (90 each), each lane
  // accumulates 4 e-pairs; cross-wave reduce via LDS. 4x shorter latency chain.
  {
    const unsigned* fp = (const unsigned*)ybuf + ((size_t)b*G_)*256;
    float2 cacc[4];
    #pragma unroll
    for (int k=0;k<4;++k) cacc[k] = make_float2(0.f,0.f);
    int g0 = wv*90;
    for (int gg=g0; gg<g0+90; ++gg){
      float wq = sc[gg];
      #pragma unroll
      for (int k=0;k<4;++k){
        float2 p = bfpair(fp[(size_t)gg*256 + ln + 64*k]);
        cacc[k].x += wq*p.x; cacc[k].y += wq*p.y;
      }
    }
    #pragma unroll
    for (int k=0;k<4;++k) cred[wv][ln + 64*k] = cacc[k];
  }
  __syncthreads();
  {
    float c0v = cred[0][tid].x + cred[1][tid].x + cred[2][tid].x + cred[3][tid].x;
    float c1v = cred[0][tid].y + cred[1][tid].y + cred[2][tid].y + cred[3][tid].y;
    int e0 = 2*tid;
    float ctx0 = encg[e0]  *(c0v - Mo) + encb[e0];
    float ctx1 = encg[e0+1]*(c1v - Mo) + encb[e0+1];
    int pc = swzcol(2*tid, b&7);   // ctx region col pair (even)
    ((unsigned*)ASlot)[((size_t)b*1536 + 512 + pc)>>1] = packbf(ctx0, ctx1);
  }
}

// ====================== in-place row softmax over VOC ==========
__global__ __launch_bounds__(256) void k_softmax(float* __restrict__ outp)
{
  __shared__ float red[8];
  const size_t row = (size_t)blockIdx.x * VOC_;
  const int tid = threadIdx.x;
  const int wv = tid >> 6, ln = tid & 63;
  float v[20];
  float mx = -1e30f;
  #pragma unroll
  for (int k=0;k<20;++k){
    int idx = tid + k*256;
    v[k] = (idx < VOC_) ? outp[row+idx] : -1e30f;
    mx = fmaxf(mx, v[k]);
  }
  #pragma unroll
  for (int mk=1;mk<64;mk<<=1) mx = fmaxf(mx,__shfl_xor(mx,mk,64));
  if (ln==0) red[wv] = mx;
  __syncthreads();
  if (tid==0) red[0]=fmaxf(fmaxf(red[0],red[1]),fmaxf(red[2],red[3]));
  __syncthreads();
  mx = red[0];
  float s=0.f;
  #pragma unroll
  for (int k=0;k<20;++k){ v[k] = __expf(v[k]-mx); s += v[k]; }
  #pragma unroll
  for (int mk=1;mk<64;mk<<=1) s += __shfl_xor(s,mk,64);
  if (ln==0) red[4+wv]=s;
  __syncthreads();
  if (tid==0) red[4]=red[4]+red[5]+red[6]+red[7];
  __syncthreads();
  float inv = 1.f/red[4];
  #pragma unroll
  for (int k=0;k<20;++k){
    int idx = tid + k*256;
    if (idx < VOC_) outp[row+idx] = v[k]*inv;
  }
}

extern "C" void kernel_launch(void* const* d_in, const int* in_sizes, int n_in,
                              void* d_out, int out_size, void* d_ws, size_t ws_size,
                              hipStream_t stream) {
  const float* features = (const float*)d_in[0];
  const int*   text     = (const int*)d_in[1];
  const float* a0    = (const float*)d_in[2];
  const float* c0    = (const float*)d_in[3];
  const float* encW  = (const float*)d_in[4];
  const float* encB  = (const float*)d_in[5];
  const float* encLNg= (const float*)d_in[6];
  const float* encLNb= (const float*)d_in[7];
  const float* attnW1= (const float*)d_in[8];
  const float* attnb1= (const float*)d_in[9];
  const float* attnW2= (const float*)d_in[10];
  const float* attnb2= (const float*)d_in[11];
  const float* attnV = (const float*)d_in[12];
  const float* attnbV= (const float*)d_in[13];
  const float* emb   = (const float*)d_in[14];
  const float* Wih   = (const float*)d_in[15];
  const float* Whh   = (const float*)d_in[16];
  const float* bih   = (const float*)d_in[17];
  const float* bhh   = (const float*)d_in[18];
  const float* lng   = (const float*)d_in[19];
  const float* lnb   = (const float*)d_in[20];
  const float* dW1   = (const float*)d_in[21];
  const float* db1   = (const float*)d_in[22];
  const float* dW2   = (const float*)d_in[23];
  const float* db2   = (const float*)d_in[24];

  uint8_t* w8 = (uint8_t*)d_ws;
  unsigned short* ybuf   = (unsigned short*)(w8);              // 47,185,920
  float*          stats  = (float*)(w8 + 47185920);            //    368,640
  float*          stats2 = (float*)(w8 + 47554560);            //    368,640
  float*          f1b    = (float*)(w8 + 47923200);            //  5,898,240
  unsigned short* ASbuf  = (unsigned short*)(w8 + 53821440);   //  7,864,320
  unsigned short* Wstep  = (unsigned short*)(w8 + 61685760);   //  6,291,456
  float*          bias_sum=(float*)(w8 + 67977216);            //      8,192
  unsigned short* W1g    = (unsigned short*)(w8 + 67985408);   //     32,768
  float*          f1c    = (float*)(w8 + 68018176);            //        256
  unsigned short* dW1t   = (unsigned short*)(w8 + 68018432);   //    262,144
  unsigned short* dW2t   = (unsigned short*)(w8 + 68280576);   //  2,621,440
  float*          cws    = (float*)(w8 + 71950592);            //    262,144
  unsigned short* a_bf   = (unsigned short*)(w8 + 72212736);   //  2,621,440
  unsigned short* d1bf   = (unsigned short*)(w8 + 74834176);   //  1,310,720

  float* outp = (float*)d_out;
  float* att  = outp + 12800000;   // [B][T][G]
  float* gsplit = outp;
  float* gtxt   = outp + 8*128*2048;

  hipLaunchKernelGGL(k_cvt, dim3(5059), dim3(256), 0, stream,
                     text, emb, Wih, Whh, bih, bhh, attnW1, attnb1,
                     encLNg, encLNb, dW1, dW2,
                     stats, Wstep, bias_sum, ASbuf, W1g, f1c, dW1t, dW2t);
  hipLaunchKernelGGL(k_enc, dim3(4,360), dim3(512), 0, stream,
                     features, encW, encB, ybuf, stats);
  hipLaunchKernelGGL((k_gemm<64,8,0>), dim3(32,20), dim3(256), 0, stream,
                     ASbuf, 1536, Wstep, 1536, bias_sum,
                     gtxt, (unsigned short*)nullptr,
                     (const float*)nullptr, (float*)nullptr, (const float*)nullptr);
  hipLaunchKernelGGL((k_gemm<32,8,1>), dim3(1,360), dim3(256), 0, stream,
                     ybuf, 512, W1g, 512, (const float*)nullptr,
                     f1b, (unsigned short*)nullptr, stats, stats2, f1c);
  hipLaunchKernelGGL(k_cellattn, dim3(128), dim3(256), 0, stream,
                     gsplit, gtxt, c0, cws, a0, lng, lnb, attnW2, attnb2, attnV, attnbV,
                     f1b, ybuf, stats2, encLNg, encLNb,
                     ASbuf, a_bf, att, 0, 0, 1);
  for (int t=0; t<T_; ++t){
    hipLaunchKernelGGL(k_gates, dim3(32,8), dim3(256), 0, stream,
                       ASbuf + (size_t)t*128*1536 + 512, Wstep, gsplit);
    int da = (t < T_-1) ? 1 : 0;
    unsigned short* slot = ASbuf + (size_t)((t+1 < T_) ? (t+1) : 0)*128*1536;
    hipLaunchKernelGGL(k_cellattn, dim3(128), dim3(256), 0, stream,
                       gsplit, gtxt + (size_t)t*128*2048, (t==0)?c0:cws, cws, a0, lng, lnb,
                       attnW2, attnb2, attnV, attnbV,
                       f1b, ybuf, stats2, encLNg, encLNb,
                       slot, a_bf + (size_t)t*128*512, att, t+1, 1, da);
  }
  hipLaunchKernelGGL((k_gemm<128,8,2>), dim3(2,20), dim3(256), 0, stream,
                     a_bf, 512, dW1t, 512, db1,
                     (float*)nullptr, d1bf, (const float*)nullptr, (float*)nullptr,
                     (const float*)nullptr);
  hipLaunchKernelGGL((k_gemm<128,4,3>), dim3(40,20), dim3(256), 0, stream,
                     d1bf, 256, dW2t, 256, db2,
                     outp, (unsigned short*)nullptr, (const float*)nullptr,
                     (float*)nullptr, (const float*)nullptr);
  hipLaunchKernelGGL(k_softmax, dim3(2560), dim3(256), 0, stream, outp);
}